// Round 18
// baseline (49.159 us; speedup 1.0000x reference)
//
#include <hip/hip_runtime.h>
#include <stdint.h>

#define E2V     600000
#define NNODES  50000
#define UCNT    500
#define DE      100
#define DOUT    100
#define NB      16
#define KTOT    3328      // 3200 (G) + 100 (x/root) + 1 (bias) + 27 pad
#define MROWS   512
#define HASHN   2048      // LDS hash (node -> last u), 500 keys
#define HCAP    64        // per-filter-block hit cap (mean ~20)
#define NREG    293       // ceil(600000/2048) filter blocks/regions
#define ECAP    96        // per-slot edge cap (mean ~12)
#define TRB2    364       // fragment-transpose blocks: 2 branches * 46592/256
#define BFN     (7*8*13*512)   // B fragment-order elems per branch (372736)

using short8 = __attribute__((ext_vector_type(8))) short;
using f32x4  = __attribute__((ext_vector_type(4))) float;

static constexpr size_t align256(size_t x){ return (x + 255) & ~size_t(255); }
static constexpr size_t OFF_HCNT = 0;                                         // 293 i32
static constexpr size_t OFF_IHEA = align256(OFF_HCNT + NREG*4);               // 512 i32
static constexpr size_t OFF_INEX = OFF_IHEA + MROWS*4;                        // 512 i32
static constexpr size_t OFF_HBUF = align256(OFF_INEX + MROWS*4);              // 293*64 u64
static constexpr size_t OFF_GM   = align256(OFF_HBUF + (size_t)NREG*HCAP*8);  // 512*3328 bf16 (frag order)
static constexpr size_t OFF_GS   = OFF_GM + (size_t)MROWS*KTOT*2;
static constexpr size_t OFF_BTM  = align256(OFF_GS + (size_t)MROWS*KTOT*2);   // BFN bf16 (frag order)
static constexpr size_t OFF_BTS  = OFF_BTM + (size_t)BFN*2;                   // total ~8.3 MB

__device__ __forceinline__ unsigned short f2b(float f){
    uint32_t u = __float_as_uint(f);
    uint32_t r = (u + 0x7FFFu + ((u >> 16) & 1u)) >> 16;
    return (unsigned short)r;
}

// fragment-order base index for A (G rows), k0 multiple of 8:
// [mt = row/16][wv = k/416][kc = (k%416)/32][lane = ((k%32)/8)*16 + row%16][8]
__device__ __forceinline__ size_t af_base(int row, int k0){
    int mt = row >> 4, lr = row & 15;
    int wv = k0 / 416, r = k0 - wv*416;
    int kc = r >> 5, hi = (r >> 3) & 3;
    return ((size_t)((mt*8 + wv)*13 + kc) << 9) + (size_t)((hi*16 + lr) << 3);
}

__device__ __forceinline__ uint32_t hh(int key){
    return (((uint32_t)key * 2654435761u) >> 16) & (HASHN - 1);
}
// LDS hash: insert (key, val) with last-wins (atomicMax on val)
__device__ __forceinline__ void hins(int* hk, int* hv, int key, int val){
    uint32_t idx = hh(key);
    while (true){
        int k = hk[idx];
        if (k == key){ atomicMax(&hv[idx], val); return; }
        if (k == -1){
            int old = atomicCAS(&hk[idx], -1, key);
            if (old == -1 || old == key){ atomicMax(&hv[idx], val); return; }
        }
        idx = (idx + 1) & (HASHN - 1);
    }
}
__device__ __forceinline__ int hlook(const int* hk, const int* hv, int key){
    uint32_t idx = hh(key);
    while (true){
        int k = hk[idx];
        if (k == key) return hv[idx];
        if (k == -1)  return -1;
        idx = (idx + 1) & (HASHN - 1);
    }
}

__device__ __forceinline__ float bt_src(const float* __restrict__ basis,
                                        const float* __restrict__ root,
                                        const float* __restrict__ bias,
                                        int k, int j){
    if (k < 3200) return basis[k*100 + j];
    if (k < 3300) return root[(k-3200)*100 + j];
    if (k == 3300) return bias[j];
    return 0.f;
}

// ---- K1: [0..292] edge filter (2048 edges each) -> per-block hit regions;
//          [293..656] fragment-order Bt build (vector stores); [657] chains. ----
__global__ __launch_bounds__(256) void k1(
        const int* __restrict__ unseen_index, const int* __restrict__ eidx,
        int* __restrict__ hcnt, uint64_t* __restrict__ hbuf,
        int* __restrict__ ihead, int* __restrict__ inext,
        const float* __restrict__ bm, const float* __restrict__ bs,
        const float* __restrict__ rm, const float* __restrict__ rs,
        const float* __restrict__ qm, const float* __restrict__ qs,
        unsigned short* __restrict__ btm, unsigned short* __restrict__ bts){
    __shared__ int hk[HASHN], hv[HASHN];
    __shared__ uint64_t sHit[HCAP];
    __shared__ int sN, sIH[MROWS];
    int bx = blockIdx.x, tid = threadIdx.x;

    if (bx < NREG){
        for (int i = tid; i < HASHN; i += 256){ hk[i] = -1; hv[i] = -1; }
        if (tid == 0) sN = 0;
        __syncthreads();
        for (int u = tid; u < UCNT; u += 256) hins(hk, hv, unseen_index[u], u);
        __syncthreads();
        #pragma unroll
        for (int rr = 0; rr < 2; ++rr){
            int e0 = bx*2048 + (rr*256 + tid)*4;
            if (e0 >= E2V) break;
            int4 d = *(const int4*)(eidx + E2V + e0);
            #pragma unroll
            for (int j = 0; j < 4; ++j){
                int dn = (j==0) ? d.x : (j==1) ? d.y : (j==2) ? d.z : d.w;
                int s = hlook(hk, hv, dn);
                if (s >= 0){
                    int e = e0 + j;
                    int srcp = hlook(hk, hv, eidx[e]);   // src membership (last-wins pos)
                    int p = atomicAdd(&sN, 1);
                    if (p < HCAP)
                        sHit[p] = ((uint64_t)(uint32_t)(srcp + 1) << 32)
                                | ((uint64_t)(uint32_t)s << 20) | (uint64_t)(uint32_t)e;
                }
            }
        }
        __syncthreads();
        int n = sN < HCAP ? sN : HCAP;
        if (tid == 0) hcnt[bx] = n;
        if (tid < n) hbuf[bx*HCAP + tid] = sHit[tid];
        return;
    }
    if (bx < NREG + TRB2){
        // fragment-order Bt: thread = one (branch, f, lane) -> one short8 store
        int w = (bx - NREG)*256 + tid;       // 0..93183
        int br = w / 46592;
        int rem = w - br*46592;
        int lane = rem & 63;
        int f = rem >> 6;                     // (t7*8 + wv)*13 + kc, 0..727
        int kc = f % 13;
        int g  = f / 13;
        int wv = g & 7, t7 = g >> 3;
        int hi = lane >> 4, lr = lane & 15;
        int tj0 = (t7 == 6) ? 84 : t7*16;
        int j = tj0 + lr;                     // always < 100
        int kbase = wv*416 + kc*32 + hi*8;
        const float* basis = br ? bs : bm;
        const float* root  = br ? rs : rm;
        const float* bias  = br ? qs : qm;
        unsigned short* bt = br ? bts : btm;
        short8 v;
        #pragma unroll
        for (int off = 0; off < 8; ++off)
            v[off] = (short)f2b(bt_src(basis, root, bias, kbase + off, j));
        *(short8*)(bt + (((size_t)f) << 9) + ((size_t)lane << 3)) = v;
        return;
    }
    // chain block
    for (int i = tid; i < HASHN; i += 256){ hk[i] = -1; hv[i] = -1; }
    for (int i = tid; i < MROWS; i += 256) sIH[i] = -1;
    __syncthreads();
    for (int u = tid; u < UCNT; u += 256) hins(hk, hv, unseen_index[u], u);
    __syncthreads();
    for (int u = tid; u < UCNT; u += 256){
        int slot = hlook(hk, hv, unseen_index[u]);
        inext[u] = atomicExch(&sIH[slot], u);
    }
    __syncthreads();
    for (int i = tid; i < MROWS; i += 256) ihead[i] = sIH[i];
}

// ---- K2: build G rows; stage row in LDS, vector short8 stores in frag order ----
__global__ __launch_bounds__(256) void k_g(
        const int* __restrict__ hcnt, const uint64_t* __restrict__ hbuf,
        const int* __restrict__ eidx,
        const int* __restrict__ etype, const int* __restrict__ rel_index,
        const int* __restrict__ node_id,
        const float* __restrict__ ent, const float* __restrict__ unseen,
        const float* __restrict__ rel,
        const float* __restrict__ am, const float* __restrict__ as_,
        unsigned short* __restrict__ Gm, unsigned short* __restrict__ Gs){
    int slot = blockIdx.x;
    int tid  = threadIdx.x;
    __shared__ int sEdge[ECAP], sNE;
    __shared__ short sSrc[ECAP];
    __shared__ __align__(16) float sM[8][200];
    __shared__ __align__(16) float sAm[8][16], sAs[8][16];
    __shared__ __align__(16) float sG[KTOT];
    __shared__ const float* sPX[8];
    __shared__ const float* sPR[8];
    __shared__ int sT[8];

    if (tid == 0) sNE = 0;
    __syncthreads();
    for (int r = tid; r < NREG; r += 256){
        int c = hcnt[r];
        for (int i = 0; i < c; ++i){
            uint64_t h = hbuf[r*HCAP + i];
            if ((int)((h >> 20) & 0xFFFu) == slot){
                int p = atomicAdd(&sNE, 1);
                if (p < ECAP){
                    sEdge[p] = (int)(h & 0xFFFFFu);
                    sSrc[p]  = (short)((int)(uint32_t)(h >> 32) - 1);
                }
            }
        }
    }
    __syncthreads();
    int nT = sNE;
    int nE = nT > ECAP ? ECAP : nT;

    float gm[16], gs[16];
    #pragma unroll
    for (int b = 0; b < NB; ++b){ gm[b] = 0.f; gs[b] = 0.f; }

    for (int c0 = 0; c0 < nE; c0 += 8){
        int kc = nE - c0; if (kc > 8) kc = 8;
        if (tid < kc){
            int e = sEdge[c0 + tid];
            sT[tid] = etype[e];
            int srcp = sSrc[c0 + tid];
            sPX[tid] = (srcp >= 0) ? unseen + (size_t)srcp*DE
                                   : ent + (size_t)node_id[eidx[e]]*DE;
            sPR[tid] = rel + (size_t)rel_index[e]*DE;
        }
        __syncthreads();
        for (int q = tid; q < kc*50; q += 256){
            int eL = q / 50, s = q % 50;
            const float* base = (s < 25) ? sPX[eL] : sPR[eL];
            int off = (s < 25) ? s*4 : (s-25)*4;
            float4 v = *(const float4*)(base + off);
            int kb = (s < 25) ? s*4 : (s-25)*4 + 100;
            *(float4*)&sM[eL][kb] = v;
        }
        if (tid < kc*16){
            int eL = tid >> 4, b = tid & 15;
            int t = sT[eL];
            sAm[eL][b] = am[t*NB + b];
            sAs[eL][b] = as_[t*NB + b];
        }
        __syncthreads();
        if (tid < 200){
            for (int e = 0; e < kc; ++e){
                float mk = sM[e][tid];
                const float4* pa = (const float4*)&sAm[e][0];
                const float4* ps = (const float4*)&sAs[e][0];
                #pragma unroll
                for (int q = 0; q < 4; ++q){
                    float4 va = pa[q], vs = ps[q];
                    gm[q*4+0] += va.x*mk; gm[q*4+1] += va.y*mk;
                    gm[q*4+2] += va.z*mk; gm[q*4+3] += va.w*mk;
                    gs[q*4+0] += vs.x*mk; gs[q*4+1] += vs.y*mk;
                    gs[q*4+2] += vs.z*mk; gs[q*4+3] += vs.w*mk;
                }
            }
        }
        __syncthreads();
    }
    float inv = 1.f / fmaxf((float)nT, 1.f);
    // ---- mu row: stage f32 in LDS, then vector bf16 stores ----
    if (tid < 200){
        #pragma unroll
        for (int b = 0; b < NB; ++b) sG[b*200 + tid] = gm[b] * inv;
    }
    if (tid < 100){
        sG[3200 + tid] = (slot < UCNT) ? unseen[(size_t)slot*DE + tid] : 0.f;
    } else if (tid == 100){
        sG[3300] = 1.f;
    } else if (tid > 100 && tid < 128){
        sG[3200 + tid] = 0.f;                 // 3301..3327 pad
    }
    __syncthreads();
    for (int v8 = tid; v8 < KTOT/8; v8 += 256){
        int k0 = v8*8;
        short8 o;
        #pragma unroll
        for (int q = 0; q < 8; ++q) o[q] = (short)f2b(sG[k0 + q]);
        *(short8*)(Gm + af_base(slot, k0)) = o;
    }
    __syncthreads();
    // ---- sigma row: overwrite first 3200 (tail identical) ----
    if (tid < 200){
        #pragma unroll
        for (int b = 0; b < NB; ++b) sG[b*200 + tid] = gs[b] * inv;
    }
    __syncthreads();
    for (int v8 = tid; v8 < KTOT/8; v8 += 256){
        int k0 = v8*8;
        short8 o;
        #pragma unroll
        for (int q = 0; q < 8; ++q) o[q] = (short)f2b(sG[k0 + q]);
        *(short8*)(Gs + af_base(slot, k0)) = o;
    }
}

// ---- K3: out = G_aug @ B_aug. Block = (br, m16, jt); 8 waves K-split (13 chunks).
//      Fragment-order operands: every load = one contiguous 1KB wave transaction.
//      Reg prefetch; LDS reduce; direct chain-scatter. ----
__global__ __launch_bounds__(512) void k_gemm(
        const unsigned short* __restrict__ Gm, const unsigned short* __restrict__ Gs,
        const unsigned short* __restrict__ Btm, const unsigned short* __restrict__ Bts,
        const int* __restrict__ ihead, const int* __restrict__ inext,
        float* __restrict__ out){
    __shared__ f32x4 red[512];
    int bid = blockIdx.x;                 // 0..447
    int br  = bid / 224;
    int w2  = bid % 224;
    int m16 = w2 & 31;                    // 32 M-tiles of 16 rows
    int jt  = w2 >> 5;                    // 7 j-tiles
    int wv  = threadIdx.x >> 6;           // k-chunk 0..7
    int lane = threadIdx.x & 63;
    const unsigned short* A  = br ? Gs : Gm;
    const unsigned short* Bt = br ? Bts : Btm;
    int rowa = lane & 15;
    int j0 = (jt == 6) ? 84 : jt*16;      // overlap trick, guard col>=96
    int col = j0 + rowa;
    const unsigned short* ap = A  + (((size_t)(m16*8 + wv)*13) << 9) + ((size_t)lane << 3);
    const unsigned short* bp = Bt + (((size_t)(jt*8 + wv)*13) << 9) + ((size_t)lane << 3);
    short8 avs[13], bvs[13];
    #pragma unroll
    for (int kc = 0; kc < 13; ++kc){
        avs[kc] = *(const short8*)(ap + kc*512);
        bvs[kc] = *(const short8*)(bp + kc*512);
    }
    f32x4 acc = {0.f, 0.f, 0.f, 0.f};
    #pragma unroll
    for (int kc = 0; kc < 13; ++kc)
        acc = __builtin_amdgcn_mfma_f32_16x16x32_bf16(avs[kc], bvs[kc], acc, 0, 0, 0);
    red[threadIdx.x] = acc;
    __syncthreads();
    if (threadIdx.x < 64){                // wave 0: reduce + epilogue
        #pragma unroll
        for (int w = 1; w < 8; ++w){
            f32x4 o = red[threadIdx.x + w*64];
            acc[0] += o[0]; acc[1] += o[1]; acc[2] += o[2]; acc[3] += o[3];
        }
        if (jt < 6 || col >= 96){
            int r0 = m16*16 + (lane >> 4)*4;
            #pragma unroll
            for (int r = 0; r < 4; ++r){
                int u = ihead[r0 + r];
                while (u >= 0){
                    if (br == 0){
                        out[(size_t)u*100 + col] = acc[r];
                        out[(size_t)(UCNT + u)*100 + col] = acc[r];
                    } else {
                        out[(size_t)(2*UCNT + u)*100 + col] = acc[r];
                    }
                    u = inext[u];
                }
            }
        }
    }
}

extern "C" void kernel_launch(void* const* d_in, const int* in_sizes, int n_in,
                              void* d_out, int out_size, void* d_ws, size_t ws_size,
                              hipStream_t stream){
    const float* ent        = (const float*)d_in[0];
    const float* rel_table  = (const float*)d_in[1];
    const float* unseen_emb = (const float*)d_in[2];
    const float* att_mu     = (const float*)d_in[3];
    const float* basis_mu   = (const float*)d_in[4];
    const float* root_mu    = (const float*)d_in[5];
    const float* bias_mu    = (const float*)d_in[6];
    const float* att_sig    = (const float*)d_in[7];
    const float* basis_sig  = (const float*)d_in[8];
    const float* root_sig   = (const float*)d_in[9];
    const float* bias_sig   = (const float*)d_in[10];
    const int* node_id      = (const int*)d_in[11];
    const int* edge_index   = (const int*)d_in[12];
    const int* edge_type    = (const int*)d_in[13];
    const int* rel_index    = (const int*)d_in[14];
    const int* unseen_index = (const int*)d_in[15];
    float* out = (float*)d_out;
    char* ws = (char*)d_ws;

    int* hcnt       = (int*)(ws + OFF_HCNT);
    int* ihead      = (int*)(ws + OFF_IHEA);
    int* inext      = (int*)(ws + OFF_INEX);
    uint64_t* hbuf  = (uint64_t*)(ws + OFF_HBUF);
    unsigned short* Gm  = (unsigned short*)(ws + OFF_GM);
    unsigned short* Gs  = (unsigned short*)(ws + OFF_GS);
    unsigned short* Btm = (unsigned short*)(ws + OFF_BTM);
    unsigned short* Bts = (unsigned short*)(ws + OFF_BTS);

    k1<<<NREG + TRB2 + 1, 256, 0, stream>>>(unseen_index, edge_index,
        hcnt, hbuf, ihead, inext,
        basis_mu, basis_sig, root_mu, root_sig, bias_mu, bias_sig, Btm, Bts);
    k_g<<<MROWS, 256, 0, stream>>>(hcnt, hbuf, edge_index, edge_type,
        rel_index, node_id, ent, unseen_emb, rel_table, att_mu, att_sig, Gm, Gs);
    k_gemm<<<448, 512, 0, stream>>>(Gm, Gs, Btm, Bts, ihead, inext, out);
}

// Round 19
// 44.324 us; speedup vs baseline: 1.1091x; 1.1091x over previous
//
#include <hip/hip_runtime.h>
#include <stdint.h>

#define E2V     600000
#define NNODES  50000
#define UCNT    500
#define DE      100
#define DOUT    100
#define NB      16
#define KTOT    3328      // 3200 (G) + 100 (x/root) + 1 (bias) + 27 pad
#define MROWS   512
#define HASHN   2048      // LDS hash (node -> last u), 500 keys
#define HCAP    64        // per-filter-block hit cap (mean ~10)
#define NREG    586       // ceil(600000/1024) filter blocks/regions
#define ECAP    96        // per-slot edge cap (mean ~12)
#define TRB     832       // 104 k-tiles * 4 j-tiles * 2 branches
#define BFN     (7*8*13*512)   // B fragment-order elems per branch (372736)

using short8 = __attribute__((ext_vector_type(8))) short;
using f32x4  = __attribute__((ext_vector_type(4))) float;

static constexpr size_t align256(size_t x){ return (x + 255) & ~size_t(255); }
static constexpr size_t OFF_HCNT = 0;                                         // 586 i32
static constexpr size_t OFF_IHEA = align256(OFF_HCNT + NREG*4);               // 512 i32
static constexpr size_t OFF_INEX = OFF_IHEA + MROWS*4;                        // 512 i32
static constexpr size_t OFF_HBUF = align256(OFF_INEX + MROWS*4);              // 586*64 u64
static constexpr size_t OFF_GM   = align256(OFF_HBUF + (size_t)NREG*HCAP*8);  // 512*3328 bf16 (frag order)
static constexpr size_t OFF_GS   = OFF_GM + (size_t)MROWS*KTOT*2;
static constexpr size_t OFF_BTM  = align256(OFF_GS + (size_t)MROWS*KTOT*2);   // BFN bf16 (frag order)
static constexpr size_t OFF_BTS  = OFF_BTM + (size_t)BFN*2;                   // total ~8.5 MB

__device__ __forceinline__ unsigned short f2b(float f){
    uint32_t u = __float_as_uint(f);
    uint32_t r = (u + 0x7FFFu + ((u >> 16) & 1u)) >> 16;
    return (unsigned short)r;
}

// fragment-order index for A (G rows): element (row, k) ->
// [mt = row/16][wv = k/416][kc = (k%416)/32][lane = ((k%32)/8)*16 + row%16][k%8]
__device__ __forceinline__ size_t af_idx(int row, int k){
    int mt = row >> 4, lr = row & 15;
    int wv = k / 416, r = k - wv*416;
    int kc = r >> 5, hi = (r >> 3) & 3, off = r & 7;
    return ((size_t)((mt*8 + wv)*13 + kc) << 9) + (size_t)((hi*16 + lr) << 3) + off;
}

__device__ __forceinline__ uint32_t hh(int key){
    return (((uint32_t)key * 2654435761u) >> 16) & (HASHN - 1);
}
// LDS hash: insert (key, val) with last-wins (atomicMax on val)
__device__ __forceinline__ void hins(int* hk, int* hv, int key, int val){
    uint32_t idx = hh(key);
    while (true){
        int k = hk[idx];
        if (k == key){ atomicMax(&hv[idx], val); return; }
        if (k == -1){
            int old = atomicCAS(&hk[idx], -1, key);
            if (old == -1 || old == key){ atomicMax(&hv[idx], val); return; }
        }
        idx = (idx + 1) & (HASHN - 1);
    }
}
__device__ __forceinline__ int hlook(const int* hk, const int* hv, int key){
    uint32_t idx = hh(key);
    while (true){
        int k = hk[idx];
        if (k == key) return hv[idx];
        if (k == -1)  return -1;
        idx = (idx + 1) & (HASHN - 1);
    }
}

__device__ __forceinline__ float bt_src(const float* __restrict__ basis,
                                        const float* __restrict__ root,
                                        const float* __restrict__ bias,
                                        int k, int j){
    if (j >= 100) return 0.f;
    if (k < 3200) return basis[k*100 + j];
    if (k < 3300) return root[(k-3200)*100 + j];
    if (k == 3300) return bias[j];
    return 0.f;
}

// ---- K1: [0..585] edge filter -> per-block hit regions (slot+src resolved);
//          [586..1417] B -> fragment-order Bt; [1418] inverse chains. ----
__global__ __launch_bounds__(256) void k1(
        const int* __restrict__ unseen_index, const int* __restrict__ eidx,
        int* __restrict__ hcnt, uint64_t* __restrict__ hbuf,
        int* __restrict__ ihead, int* __restrict__ inext,
        const float* __restrict__ bm, const float* __restrict__ bs,
        const float* __restrict__ rm, const float* __restrict__ rs,
        const float* __restrict__ qm, const float* __restrict__ qs,
        unsigned short* __restrict__ btm, unsigned short* __restrict__ bts){
    __shared__ int hk[HASHN], hv[HASHN];
    __shared__ uint64_t sHit[HCAP];
    __shared__ int sN, sIH[MROWS];
    int bx = blockIdx.x, tid = threadIdx.x;

    if (bx < NREG){
        for (int i = tid; i < HASHN; i += 256){ hk[i] = -1; hv[i] = -1; }
        if (tid == 0) sN = 0;
        __syncthreads();
        for (int u = tid; u < UCNT; u += 256) hins(hk, hv, unseen_index[u], u);
        __syncthreads();
        int e0 = bx*1024 + tid*4;
        if (e0 < E2V){
            int4 d = *(const int4*)(eidx + E2V + e0);
            #pragma unroll
            for (int j = 0; j < 4; ++j){
                int dn = (j==0) ? d.x : (j==1) ? d.y : (j==2) ? d.z : d.w;
                int s = hlook(hk, hv, dn);
                if (s >= 0){
                    int e = e0 + j;
                    int srcp = hlook(hk, hv, eidx[e]);   // src membership (last-wins pos)
                    int p = atomicAdd(&sN, 1);
                    if (p < HCAP)
                        sHit[p] = ((uint64_t)(uint32_t)(srcp + 1) << 32)
                                | ((uint64_t)(uint32_t)s << 20) | (uint64_t)(uint32_t)e;
                }
            }
        }
        __syncthreads();
        int n = sN < HCAP ? sN : HCAP;
        if (tid == 0) hcnt[bx] = n;
        if (tid < n) hbuf[bx*HCAP + tid] = sHit[tid];
        return;
    }
    if (bx < NREG + TRB){
        int b2 = bx - NREG;
        int kt = b2 % 104, jt4 = (b2 / 104) & 3, br = b2 / 416;
        const float* basis = br ? bs : bm;
        const float* root  = br ? rs : rm;
        const float* bias  = br ? qs : qm;
        unsigned short* bt = br ? bts : btm;
        int k0 = kt*32, j0t = jt4*32;
        for (int q = tid; q < 1024; q += 256){
            int kk = q >> 5, jj = q & 31;       // consecutive tid -> consecutive j (coalesced read)
            int k = k0 + kk, j = j0t + jj;
            if (j >= 100) continue;
            unsigned short hv16 = f2b(bt_src(basis, root, bias, k, j));
            int wv = k / 416, r = k - wv*416;
            int kc = r >> 5, hi = (r >> 3) & 3, off = r & 7;
            #pragma unroll
            for (int t7 = 0; t7 < 7; ++t7){     // write every j-tile containing col j
                int tj0 = (t7 == 6) ? 84 : t7*16;
                int lr = j - tj0;
                if (lr >= 0 && lr < 16){
                    size_t idx = ((size_t)((t7*8 + wv)*13 + kc) << 9)
                               + (size_t)((hi*16 + lr) << 3) + off;
                    bt[idx] = hv16;
                }
            }
        }
        return;
    }
    // chain block
    for (int i = tid; i < HASHN; i += 256){ hk[i] = -1; hv[i] = -1; }
    for (int i = tid; i < MROWS; i += 256) sIH[i] = -1;
    __syncthreads();
    for (int u = tid; u < UCNT; u += 256) hins(hk, hv, unseen_index[u], u);
    __syncthreads();
    for (int u = tid; u < UCNT; u += 256){
        int slot = hlook(hk, hv, unseen_index[u]);
        inext[u] = atomicExch(&sIH[slot], u);
    }
    __syncthreads();
    for (int i = tid; i < MROWS; i += 256) ihead[i] = sIH[i];
}

// ---- K2: build G rows in fragment order: G[slot] = [ sum/cnt | x | 1 | 0 ] bf16 ----
__global__ __launch_bounds__(256) void k_g(
        const int* __restrict__ hcnt, const uint64_t* __restrict__ hbuf,
        const int* __restrict__ eidx,
        const int* __restrict__ etype, const int* __restrict__ rel_index,
        const int* __restrict__ node_id,
        const float* __restrict__ ent, const float* __restrict__ unseen,
        const float* __restrict__ rel,
        const float* __restrict__ am, const float* __restrict__ as_,
        unsigned short* __restrict__ Gm, unsigned short* __restrict__ Gs){
    int slot = blockIdx.x;
    int tid  = threadIdx.x;
    __shared__ int sEdge[ECAP], sNE;
    __shared__ short sSrc[ECAP];
    __shared__ __align__(16) float sM[8][200];
    __shared__ __align__(16) float sAm[8][16], sAs[8][16];
    __shared__ const float* sPX[8];
    __shared__ const float* sPR[8];
    __shared__ int sT[8];

    if (tid == 0) sNE = 0;
    __syncthreads();
    for (int r = tid; r < NREG; r += 256){
        int c = hcnt[r];
        for (int i = 0; i < c; ++i){
            uint64_t h = hbuf[r*HCAP + i];
            if ((int)((h >> 20) & 0xFFFu) == slot){
                int p = atomicAdd(&sNE, 1);
                if (p < ECAP){
                    sEdge[p] = (int)(h & 0xFFFFFu);
                    sSrc[p]  = (short)((int)(uint32_t)(h >> 32) - 1);
                }
            }
        }
    }
    __syncthreads();
    int nT = sNE;
    int nE = nT > ECAP ? ECAP : nT;

    float gm[16], gs[16];
    #pragma unroll
    for (int b = 0; b < NB; ++b){ gm[b] = 0.f; gs[b] = 0.f; }

    for (int c0 = 0; c0 < nE; c0 += 8){
        int kc = nE - c0; if (kc > 8) kc = 8;
        if (tid < kc){
            int e = sEdge[c0 + tid];
            sT[tid] = etype[e];
            int srcp = sSrc[c0 + tid];
            sPX[tid] = (srcp >= 0) ? unseen + (size_t)srcp*DE
                                   : ent + (size_t)node_id[eidx[e]]*DE;
            sPR[tid] = rel + (size_t)rel_index[e]*DE;
        }
        __syncthreads();
        for (int q = tid; q < kc*50; q += 256){
            int eL = q / 50, s = q % 50;
            const float* base = (s < 25) ? sPX[eL] : sPR[eL];
            int off = (s < 25) ? s*4 : (s-25)*4;
            float4 v = *(const float4*)(base + off);
            int kb = (s < 25) ? s*4 : (s-25)*4 + 100;
            *(float4*)&sM[eL][kb] = v;
        }
        if (tid < kc*16){
            int eL = tid >> 4, b = tid & 15;
            int t = sT[eL];
            sAm[eL][b] = am[t*NB + b];
            sAs[eL][b] = as_[t*NB + b];
        }
        __syncthreads();
        if (tid < 200){
            for (int e = 0; e < kc; ++e){
                float mk = sM[e][tid];
                const float4* pa = (const float4*)&sAm[e][0];
                const float4* ps = (const float4*)&sAs[e][0];
                #pragma unroll
                for (int q = 0; q < 4; ++q){
                    float4 va = pa[q], vs = ps[q];
                    gm[q*4+0] += va.x*mk; gm[q*4+1] += va.y*mk;
                    gm[q*4+2] += va.z*mk; gm[q*4+3] += va.w*mk;
                    gs[q*4+0] += vs.x*mk; gs[q*4+1] += vs.y*mk;
                    gs[q*4+2] += vs.z*mk; gs[q*4+3] += vs.w*mk;
                }
            }
        }
        __syncthreads();
    }
    float inv = 1.f / fmaxf((float)nT, 1.f);
    if (tid < 200){
        #pragma unroll
        for (int b = 0; b < NB; ++b){
            int k = b*200 + tid;
            size_t ix = af_idx(slot, k);
            Gm[ix] = f2b(gm[b] * inv);
            Gs[ix] = f2b(gs[b] * inv);
        }
    }
    if (tid < 100){
        float xv = (slot < UCNT) ? unseen[(size_t)slot*DE + tid] : 0.f;
        unsigned short h = f2b(xv);
        size_t ix = af_idx(slot, 3200 + tid);
        Gm[ix] = h; Gs[ix] = h;
    } else if (tid == 100){
        size_t ix = af_idx(slot, 3300);
        Gm[ix] = f2b(1.f); Gs[ix] = f2b(1.f);
    } else if (tid > 100 && tid < 128){
        size_t ix = af_idx(slot, 3200 + tid);    // 3301..3327 pad
        Gm[ix] = 0; Gs[ix] = 0;
    }
}

// ---- K3: out = G_aug @ B_aug. Block = (br, m16, jt); 8 waves K-split (13 chunks).
//      Operands in FRAGMENT ORDER: every load = one contiguous 1KB wave
//      transaction. Reg prefetch; LDS reduce; direct chain-scatter. ----
__global__ __launch_bounds__(512) void k_gemm(
        const unsigned short* __restrict__ Gm, const unsigned short* __restrict__ Gs,
        const unsigned short* __restrict__ Btm, const unsigned short* __restrict__ Bts,
        const int* __restrict__ ihead, const int* __restrict__ inext,
        float* __restrict__ out){
    __shared__ f32x4 red[512];
    int bid = blockIdx.x;                 // 0..447
    int br  = bid / 224;
    int w2  = bid % 224;
    int m16 = w2 & 31;                    // 32 M-tiles of 16 rows
    int jt  = w2 >> 5;                    // 7 j-tiles
    int wv  = threadIdx.x >> 6;           // k-chunk 0..7
    int lane = threadIdx.x & 63;
    const unsigned short* A  = br ? Gs : Gm;
    const unsigned short* Bt = br ? Bts : Btm;
    int rowa = lane & 15;
    int j0 = (jt == 6) ? 84 : jt*16;      // overlap trick, guard col>=96
    int col = j0 + rowa;
    const unsigned short* ap = A  + (((size_t)(m16*8 + wv)*13) << 9) + ((size_t)lane << 3);
    const unsigned short* bp = Bt + (((size_t)(jt*8 + wv)*13) << 9) + ((size_t)lane << 3);
    // prefetch ALL fragments into registers (coalesced 1KB wave loads)
    short8 avs[13], bvs[13];
    #pragma unroll
    for (int kc = 0; kc < 13; ++kc){
        avs[kc] = *(const short8*)(ap + kc*512);
        bvs[kc] = *(const short8*)(bp + kc*512);
    }
    f32x4 acc = {0.f, 0.f, 0.f, 0.f};
    #pragma unroll
    for (int kc = 0; kc < 13; ++kc)
        acc = __builtin_amdgcn_mfma_f32_16x16x32_bf16(avs[kc], bvs[kc], acc, 0, 0, 0);
    red[threadIdx.x] = acc;
    __syncthreads();
    if (threadIdx.x < 64){                // wave 0: reduce + epilogue
        #pragma unroll
        for (int w = 1; w < 8; ++w){
            f32x4 o = red[threadIdx.x + w*64];
            acc[0] += o[0]; acc[1] += o[1]; acc[2] += o[2]; acc[3] += o[3];
        }
        if (jt < 6 || col >= 96){
            int r0 = m16*16 + (lane >> 4)*4;
            #pragma unroll
            for (int r = 0; r < 4; ++r){
                int u = ihead[r0 + r];
                while (u >= 0){
                    if (br == 0){
                        out[(size_t)u*100 + col] = acc[r];
                        out[(size_t)(UCNT + u)*100 + col] = acc[r];
                    } else {
                        out[(size_t)(2*UCNT + u)*100 + col] = acc[r];
                    }
                    u = inext[u];
                }
            }
        }
    }
}

extern "C" void kernel_launch(void* const* d_in, const int* in_sizes, int n_in,
                              void* d_out, int out_size, void* d_ws, size_t ws_size,
                              hipStream_t stream){
    const float* ent        = (const float*)d_in[0];
    const float* rel_table  = (const float*)d_in[1];
    const float* unseen_emb = (const float*)d_in[2];
    const float* att_mu     = (const float*)d_in[3];
    const float* basis_mu   = (const float*)d_in[4];
    const float* root_mu    = (const float*)d_in[5];
    const float* bias_mu    = (const float*)d_in[6];
    const float* att_sig    = (const float*)d_in[7];
    const float* basis_sig  = (const float*)d_in[8];
    const float* root_sig   = (const float*)d_in[9];
    const float* bias_sig   = (const float*)d_in[10];
    const int* node_id      = (const int*)d_in[11];
    const int* edge_index   = (const int*)d_in[12];
    const int* edge_type    = (const int*)d_in[13];
    const int* rel_index    = (const int*)d_in[14];
    const int* unseen_index = (const int*)d_in[15];
    float* out = (float*)d_out;
    char* ws = (char*)d_ws;

    int* hcnt       = (int*)(ws + OFF_HCNT);
    int* ihead      = (int*)(ws + OFF_IHEA);
    int* inext      = (int*)(ws + OFF_INEX);
    uint64_t* hbuf  = (uint64_t*)(ws + OFF_HBUF);
    unsigned short* Gm  = (unsigned short*)(ws + OFF_GM);
    unsigned short* Gs  = (unsigned short*)(ws + OFF_GS);
    unsigned short* Btm = (unsigned short*)(ws + OFF_BTM);
    unsigned short* Bts = (unsigned short*)(ws + OFF_BTS);

    k1<<<NREG + TRB + 1, 256, 0, stream>>>(unseen_index, edge_index,
        hcnt, hbuf, ihead, inext,
        basis_mu, basis_sig, root_mu, root_sig, bias_mu, bias_sig, Btm, Bts);
    k_g<<<MROWS, 256, 0, stream>>>(hcnt, hbuf, edge_index, edge_type,
        rel_index, node_id, ent, unseen_emb, rel_table, att_mu, att_sig, Gm, Gs);
    k_gemm<<<448, 512, 0, stream>>>(Gm, Gs, Btm, Bts, ihead, inext, out);
}